// Round 1
// baseline (1873.061 us; speedup 1.0000x reference)
//
#include <hip/hip_runtime.h>
#include <math.h>

// GIN: N=100000 nodes, E=1600000 edges, F=D=64, L=3 layers, C=10 classes.
// Strategy:
//   - CSR build (by dst) once per launch: hist -> 1-block scan -> scatter.
//   - k_agg: wave-per-node, coalesced 256B gather per edge (no divergence).
//   - k_gemm: thread-per-node, 64 f32 accumulators, input staged via LDS in
//     16-col chunks (pad 17), W via wave-uniform s_loads. Optional fused BN+ReLU
//     on the input (for the second GEMM of each layer).
//   - BN stats: coalesced column-sum pass (lane==column invariant) -> block
//     partials -> 1-block finalize into A,B (h = relu(z*A+B)).
//   - Head: logits accumulated per layer; final log_softmax -> d_out.

#define BN_EPS 1e-5f

__global__ void k_hist(const int* __restrict__ dst, int* __restrict__ counts, int E) {
  int e = blockIdx.x * blockDim.x + threadIdx.x;
  if (e < E) atomicAdd(&counts[dst[e]], 1);
}

__global__ void k_scan(const int* __restrict__ counts, int* __restrict__ offs,
                       int* __restrict__ cursor, int N) {
  __shared__ int sums[1024];
  int t = threadIdx.x;
  int T = blockDim.x;
  int chunk = (N + T - 1) / T;
  int lo = min(t * chunk, N);
  int hi = min(lo + chunk, N);
  int s = 0;
  for (int i = lo; i < hi; i++) s += counts[i];
  sums[t] = s;
  __syncthreads();
  for (int o = 1; o < T; o <<= 1) {
    int add = (t >= o) ? sums[t - o] : 0;
    __syncthreads();
    sums[t] += add;
    __syncthreads();
  }
  int run = sums[t] - s;  // exclusive prefix
  for (int i = lo; i < hi; i++) {
    offs[i] = run;
    cursor[i] = run;
    run += counts[i];
  }
  if (t == T - 1) offs[N] = run;
}

__global__ void k_scatter(const int* __restrict__ src, const int* __restrict__ dst,
                          int* __restrict__ cursor, int* __restrict__ csr, int E) {
  int e = blockIdx.x * blockDim.x + threadIdx.x;
  if (e < E) {
    int p = atomicAdd(&cursor[dst[e]], 1);
    csr[p] = src[e];
  }
}

// wave-per-node aggregation: v[n] = h[n] + sum_{e in CSR[n]} h[src_e]
__global__ __launch_bounds__(256) void k_agg(
    const float* __restrict__ h, const int* __restrict__ offs,
    const int* __restrict__ csr, float* __restrict__ vout, int N) {
  int gid = blockIdx.x * blockDim.x + threadIdx.x;
  int wid = __builtin_amdgcn_readfirstlane(gid >> 6);  // node id, wave-uniform
  int lane = threadIdx.x & 63;
  if (wid >= N) return;
  int e0 = offs[wid];
  int e1 = offs[wid + 1];
  float acc = h[(size_t)wid * 64 + lane];
  int e = e0;
  for (; e + 4 <= e1; e += 4) {  // 4 gathers in flight
    int s0 = csr[e], s1 = csr[e + 1], s2 = csr[e + 2], s3 = csr[e + 3];
    float a0 = h[(size_t)s0 * 64 + lane];
    float a1 = h[(size_t)s1 * 64 + lane];
    float a2 = h[(size_t)s2 * 64 + lane];
    float a3 = h[(size_t)s3 * 64 + lane];
    acc += a0 + a1 + a2 + a3;
  }
  for (; e < e1; e++) acc += h[(size_t)csr[e] * 64 + lane];
  vout[(size_t)wid * 64 + lane] = acc;
}

// thread-per-node GEMM: z[n] = act(vin[n]) @ W + bias, act = BN+ReLU if dobn.
// vin/zout may alias (in-place safe: each block reads only its own 256 rows,
// all staging reads complete before the post-loop stores).
__global__ __launch_bounds__(256) void k_gemm(
    const float* vin, float* zout, const float* __restrict__ W,
    const float* __restrict__ bias, const float* __restrict__ AB, int dobn, int N) {
  __shared__ float vs[256 * 17];
  int tid = threadIdx.x;
  int n0 = blockIdx.x * 256;
  int n = n0 + tid;
  float acc[64];
#pragma unroll
  for (int d = 0; d < 64; d++) acc[d] = 0.f;
#pragma unroll 1
  for (int fb = 0; fb < 64; fb += 16) {
    __syncthreads();
#pragma unroll
    for (int g = 0; g < 4; g++) {  // stage 256 rows x 16 cols, coalesced
      int r = g * 64 + (tid >> 2);
      int q = tid & 3;
      int rn = n0 + r;
      float4 t = (rn < N) ? *(const float4*)(vin + (size_t)rn * 64 + fb + 4 * q)
                          : make_float4(0.f, 0.f, 0.f, 0.f);
      int base = r * 17 + 4 * q;
      vs[base] = t.x;
      vs[base + 1] = t.y;
      vs[base + 2] = t.z;
      vs[base + 3] = t.w;
    }
    __syncthreads();
    for (int fc = 0; fc < 16; fc++) {
      int f = fb + fc;
      float vf = vs[tid * 17 + fc];
      if (dobn) vf = fmaxf(vf * AB[f] + AB[64 + f], 0.f);
      const float* wr = W + f * 64;  // wave-uniform -> s_loads
#pragma unroll
      for (int d = 0; d < 64; d++) acc[d] += vf * wr[d];
    }
  }
  if (n < N) {
    float* zr = zout + (size_t)n * 64;
#pragma unroll
    for (int d = 0; d < 64; d += 4)
      *(float4*)(zr + d) = make_float4(acc[d] + bias[d], acc[d + 1] + bias[d + 1],
                                       acc[d + 2] + bias[d + 2], acc[d + 3] + bias[d + 3]);
  }
}

// column sums/sumsq: grid-stride with stride % 64 == 0 so lane <-> column.
__global__ void k_colstats(const float* __restrict__ z, float* __restrict__ partials,
                           int N) {
  __shared__ float ls[4 * 64], ls2[4 * 64];
  int lane = threadIdx.x & 63;
  int w = threadIdx.x >> 6;
  float s = 0.f, s2 = 0.f;
  size_t total = (size_t)N * 64;
  size_t stride = (size_t)gridDim.x * blockDim.x;
  for (size_t i = (size_t)blockIdx.x * blockDim.x + threadIdx.x; i < total; i += stride) {
    float x = z[i];
    s += x;
    s2 += x * x;
  }
  ls[w * 64 + lane] = s;
  ls2[w * 64 + lane] = s2;
  __syncthreads();
  if (threadIdx.x < 64) {
    float a = 0.f, b = 0.f;
#pragma unroll
    for (int ww = 0; ww < 4; ww++) {
      a += ls[ww * 64 + threadIdx.x];
      b += ls2[ww * 64 + threadIdx.x];
    }
    partials[blockIdx.x * 128 + threadIdx.x] = a;
    partials[blockIdx.x * 128 + 64 + threadIdx.x] = b;
  }
}

__global__ void k_bnfin(const float* __restrict__ partials, int nparts,
                        const float* __restrict__ g, const float* __restrict__ be,
                        float* __restrict__ AB, int N) {
  int f = threadIdx.x;
  if (f < 64) {
    float s = 0.f, s2 = 0.f;
    for (int p = 0; p < nparts; p++) {
      s += partials[p * 128 + f];
      s2 += partials[p * 128 + 64 + f];
    }
    float inv_n = 1.f / (float)N;
    float mu = s * inv_n;
    float var = s2 * inv_n - mu * mu;
    float is = rsqrtf(var + BN_EPS);
    float A = is * g[f];
    AB[f] = A;
    AB[64 + f] = be[f] - mu * A;
  }
}

// logits[n] = x[n] @ fcW0 + sum_l fcb[l]
__global__ __launch_bounds__(256) void k_head_init(
    const float* __restrict__ x, const float* __restrict__ fcW0,
    const float* __restrict__ fcb, float* __restrict__ logits, int N) {
  __shared__ float vs[256 * 17];
  int tid = threadIdx.x;
  int n0 = blockIdx.x * 256;
  int n = n0 + tid;
  float acc[10];
#pragma unroll
  for (int c = 0; c < 10; c++) acc[c] = 0.f;
#pragma unroll 1
  for (int fb = 0; fb < 64; fb += 16) {
    __syncthreads();
#pragma unroll
    for (int g = 0; g < 4; g++) {
      int r = g * 64 + (tid >> 2);
      int q = tid & 3;
      int rn = n0 + r;
      float4 t = (rn < N) ? *(const float4*)(x + (size_t)rn * 64 + fb + 4 * q)
                          : make_float4(0.f, 0.f, 0.f, 0.f);
      int base = r * 17 + 4 * q;
      vs[base] = t.x;
      vs[base + 1] = t.y;
      vs[base + 2] = t.z;
      vs[base + 3] = t.w;
    }
    __syncthreads();
    for (int fc = 0; fc < 16; fc++) {
      int f = fb + fc;
      float vf = vs[tid * 17 + fc];
      const float* wr = fcW0 + f * 10;
#pragma unroll
      for (int c = 0; c < 10; c++) acc[c] += vf * wr[c];
    }
  }
  if (n < N) {
    float* lr = logits + (size_t)n * 10;
#pragma unroll
    for (int c = 0; c < 10; c++)
      lr[c] = acc[c] + (fcb[c] + fcb[10 + c] + fcb[20 + c] + fcb[30 + c]);
  }
}

// h = relu(z*A+B); store h; logits += h @ fcWl
__global__ __launch_bounds__(256) void k_bn_head(
    const float* __restrict__ z, const float* __restrict__ AB,
    float* __restrict__ hout, const float* __restrict__ fcWl,
    float* __restrict__ logits, int N) {
  __shared__ float vs[256 * 17];
  int tid = threadIdx.x;
  int n0 = blockIdx.x * 256;
  int n = n0 + tid;
  float acc[10];
#pragma unroll
  for (int c = 0; c < 10; c++) acc[c] = 0.f;
#pragma unroll 1
  for (int fb = 0; fb < 64; fb += 16) {
    __syncthreads();
#pragma unroll
    for (int g = 0; g < 4; g++) {
      int r = g * 64 + (tid >> 2);
      int q = tid & 3;
      int rn = n0 + r;
      float4 t = (rn < N) ? *(const float4*)(z + (size_t)rn * 64 + fb + 4 * q)
                          : make_float4(0.f, 0.f, 0.f, 0.f);
      int base = r * 17 + 4 * q;
      vs[base] = t.x;
      vs[base + 1] = t.y;
      vs[base + 2] = t.z;
      vs[base + 3] = t.w;
    }
    __syncthreads();
    float tl[16];
#pragma unroll
    for (int fc = 0; fc < 16; fc++) {
      int f = fb + fc;
      float val = vs[tid * 17 + fc] * AB[f] + AB[64 + f];
      tl[fc] = fmaxf(val, 0.f);
      const float* wr = fcWl + f * 10;
#pragma unroll
      for (int c = 0; c < 10; c++) acc[c] += tl[fc] * wr[c];
    }
    __syncthreads();
#pragma unroll
    for (int fc = 0; fc < 16; fc++) vs[tid * 17 + fc] = tl[fc];
    __syncthreads();
#pragma unroll
    for (int g = 0; g < 4; g++) {  // coalesced h store via LDS bounce
      int r = g * 64 + (tid >> 2);
      int q = tid & 3;
      int rn = n0 + r;
      if (rn < N) {
        int base = r * 17 + 4 * q;
        *(float4*)(hout + (size_t)rn * 64 + fb + 4 * q) =
            make_float4(vs[base], vs[base + 1], vs[base + 2], vs[base + 3]);
      }
    }
  }
  if (n < N) {
    float* lr = logits + (size_t)n * 10;
#pragma unroll
    for (int c = 0; c < 10; c++) lr[c] += acc[c];
  }
}

__global__ void k_logsoftmax(const float* __restrict__ logits, float* __restrict__ out,
                             int N) {
  int n = blockIdx.x * blockDim.x + threadIdx.x;
  if (n >= N) return;
  const float* lr = logits + (size_t)n * 10;
  float v[10];
  float m = -INFINITY;
#pragma unroll
  for (int c = 0; c < 10; c++) {
    v[c] = lr[c];
    m = fmaxf(m, v[c]);
  }
  float s = 0.f;
#pragma unroll
  for (int c = 0; c < 10; c++) s += expf(v[c] - m);
  float l = logf(s) + m;
  float* orow = out + (size_t)n * 10;
#pragma unroll
  for (int c = 0; c < 10; c++) orow[c] = v[c] - l;
}

extern "C" void kernel_launch(void* const* d_in, const int* in_sizes, int n_in,
                              void* d_out, int out_size, void* d_ws, size_t ws_size,
                              hipStream_t stream) {
  const float* x = (const float*)d_in[0];
  const int* ei = (const int*)d_in[1];
  const float* W1 = (const float*)d_in[2];
  const float* b1 = (const float*)d_in[3];
  const float* g1 = (const float*)d_in[4];
  const float* be1 = (const float*)d_in[5];
  const float* W2 = (const float*)d_in[6];
  const float* b2 = (const float*)d_in[7];
  const float* gbn = (const float*)d_in[8];
  const float* bbn = (const float*)d_in[9];
  const float* fcW = (const float*)d_in[10];
  const float* fcb = (const float*)d_in[11];
  float* out = (float*)d_out;

  const int N = in_sizes[0] / 64;
  const int E = in_sizes[1] / 2;
  const int* src = ei;
  const int* dst = ei + E;

  char* ws = (char*)d_ws;
  size_t off = 0;
  auto alloc = [&](size_t bytes) -> void* {
    void* p = ws + off;
    off = (off + bytes + 255) & ~(size_t)255;
    return p;
  };
  int* counts = (int*)alloc((size_t)N * 4);
  int* offs = (int*)alloc((size_t)(N + 1) * 4);
  int* cursor = (int*)alloc((size_t)N * 4);
  int* csr = (int*)alloc((size_t)E * 4);
  float* hbuf = (float*)alloc((size_t)N * 64 * 4);
  float* zbuf = (float*)alloc((size_t)N * 64 * 4);
  float* vbuf = (float*)alloc((size_t)N * 64 * 4);
  float* logits = (float*)alloc((size_t)N * 10 * 4);
  float* partials = (float*)alloc(256 * 128 * 4);
  float* AB = (float*)alloc(128 * 4);
  (void)ws_size;
  (void)n_in;
  (void)out_size;

  hipMemsetAsync(counts, 0, (size_t)N * 4, stream);
  int eb = (E + 255) / 256;
  int nb = (N + 255) / 256;
  k_hist<<<eb, 256, 0, stream>>>(dst, counts, E);
  k_scan<<<1, 1024, 0, stream>>>(counts, offs, cursor, N);
  k_scatter<<<eb, 256, 0, stream>>>(src, dst, cursor, csr, E);
  k_head_init<<<nb, 256, 0, stream>>>(x, fcW, fcb, logits, N);

  const float* hin = x;
  for (int l = 0; l < 3; l++) {
    k_agg<<<(N * 64 + 255) / 256, 256, 0, stream>>>(hin, offs, csr, vbuf, N);
    k_gemm<<<nb, 256, 0, stream>>>(vbuf, zbuf, W1 + l * 4096, b1 + l * 64, AB, 0, N);
    k_colstats<<<256, 256, 0, stream>>>(zbuf, partials, N);
    k_bnfin<<<1, 64, 0, stream>>>(partials, 256, g1 + l * 64, be1 + l * 64, AB, N);
    k_gemm<<<nb, 256, 0, stream>>>(zbuf, zbuf, W2 + l * 4096, b2 + l * 64, AB, 1, N);
    k_colstats<<<256, 256, 0, stream>>>(zbuf, partials, N);
    k_bnfin<<<1, 64, 0, stream>>>(partials, 256, gbn + l * 64, bbn + l * 64, AB, N);
    k_bn_head<<<nb, 256, 0, stream>>>(zbuf, AB, hbuf, fcW + (l + 1) * 640, logits, N);
    hin = hbuf;
  }
  k_logsoftmax<<<nb, 256, 0, stream>>>(logits, out, N);
}

// Round 2
// 1641.493 us; speedup vs baseline: 1.1411x; 1.1411x over previous
//
#include <hip/hip_runtime.h>
#include <math.h>

// GIN: N=100000 nodes, E=1600000 edges, F=D=64, L=3 layers, C=10 classes.
// Strategy:
//   - CSR build (by dst) once per launch: hist -> 3-pass device-wide scan ->
//     scatter. (R2: replaced 1-block serial scan [231 us!] with multi-block.)
//   - k_agg: wave-per-node, coalesced 256B gather per edge (no divergence).
//   - k_gemm: thread-per-node, 64 f32 accumulators, input staged via LDS in
//     16-col chunks (pad 17), W via wave-uniform s_loads. Optional fused BN+ReLU
//     on the input (for the second GEMM of each layer).
//   - BN stats: coalesced column-sum pass (lane==column invariant) -> block
//     partials -> 1-block finalize into A,B (h = relu(z*A+B)).
//   - Head: logits accumulated per layer; final log_softmax -> d_out.

#define BN_EPS 1e-5f
#define SCAN_CHUNK 512  // elements per block in the device-wide scan (N<=131072)

__global__ void k_hist(const int* __restrict__ dst, int* __restrict__ counts, int E) {
  int e = blockIdx.x * blockDim.x + threadIdx.x;
  if (e < E) atomicAdd(&counts[dst[e]], 1);
}

// scan pass 1: per-block sum of a 512-element chunk of counts
__global__ __launch_bounds__(256) void k_blocksum(const int* __restrict__ counts,
                                                  int* __restrict__ blocksums, int N) {
  __shared__ int ls[256];
  int t = threadIdx.x;
  int base = blockIdx.x * SCAN_CHUNK;
  int i0 = base + 2 * t, i1 = i0 + 1;
  int c0 = (i0 < N) ? counts[i0] : 0;
  int c1 = (i1 < N) ? counts[i1] : 0;
  ls[t] = c0 + c1;
  __syncthreads();
  for (int o = 128; o > 0; o >>= 1) {
    if (t < o) ls[t] += ls[t + o];
    __syncthreads();
  }
  if (t == 0) blocksums[blockIdx.x] = ls[0];
}

// scan pass 2: single block scans <=256 block sums (exclusive)
__global__ __launch_bounds__(256) void k_scanblock(const int* __restrict__ blocksums,
                                                    int* __restrict__ blockoffs, int nblk) {
  __shared__ int ts[256];
  int t = threadIdx.x;
  int v = (t < nblk) ? blocksums[t] : 0;
  ts[t] = v;
  __syncthreads();
  for (int o = 1; o < 256; o <<= 1) {
    int add = (t >= o) ? ts[t - o] : 0;
    __syncthreads();
    ts[t] += add;
    __syncthreads();
  }
  blockoffs[t] = ts[t] - v;  // exclusive
}

// scan pass 3: per-block exclusive scan of its chunk, offset by blockoffs
__global__ __launch_bounds__(256) void k_scanfinal(
    const int* __restrict__ counts, const int* __restrict__ blockoffs,
    int* __restrict__ offs, int* __restrict__ cursor, int N) {
  __shared__ int ts[256];
  int t = threadIdx.x;
  int base = blockIdx.x * SCAN_CHUNK;
  int i0 = base + 2 * t, i1 = i0 + 1;
  int c0 = (i0 < N) ? counts[i0] : 0;
  int c1 = (i1 < N) ? counts[i1] : 0;
  int s = c0 + c1;
  ts[t] = s;
  __syncthreads();
  for (int o = 1; o < 256; o <<= 1) {
    int add = (t >= o) ? ts[t - o] : 0;
    __syncthreads();
    ts[t] += add;
    __syncthreads();
  }
  int excl = ts[t] - s + blockoffs[blockIdx.x];
  if (i0 < N) {
    offs[i0] = excl;
    cursor[i0] = excl;
  }
  if (i1 < N) {
    offs[i1] = excl + c0;
    cursor[i1] = excl + c0;
  }
  if (i0 == N - 1) offs[N] = excl + c0;
  else if (i1 == N - 1) offs[N] = excl + c0 + c1;
}

__global__ void k_scatter(const int* __restrict__ src, const int* __restrict__ dst,
                          int* __restrict__ cursor, int* __restrict__ csr, int E) {
  int e = blockIdx.x * blockDim.x + threadIdx.x;
  if (e < E) {
    int p = atomicAdd(&cursor[dst[e]], 1);
    csr[p] = src[e];
  }
}

// wave-per-node aggregation: v[n] = h[n] + sum_{e in CSR[n]} h[src_e]
__global__ __launch_bounds__(256) void k_agg(
    const float* __restrict__ h, const int* __restrict__ offs,
    const int* __restrict__ csr, float* __restrict__ vout, int N) {
  int gid = blockIdx.x * blockDim.x + threadIdx.x;
  int wid = __builtin_amdgcn_readfirstlane(gid >> 6);  // node id, wave-uniform
  int lane = threadIdx.x & 63;
  if (wid >= N) return;
  int e0 = offs[wid];
  int e1 = offs[wid + 1];
  float acc = h[(size_t)wid * 64 + lane];
  int e = e0;
  for (; e + 4 <= e1; e += 4) {  // 4 gathers in flight
    int s0 = csr[e], s1 = csr[e + 1], s2 = csr[e + 2], s3 = csr[e + 3];
    float a0 = h[(size_t)s0 * 64 + lane];
    float a1 = h[(size_t)s1 * 64 + lane];
    float a2 = h[(size_t)s2 * 64 + lane];
    float a3 = h[(size_t)s3 * 64 + lane];
    acc += a0 + a1 + a2 + a3;
  }
  for (; e < e1; e++) acc += h[(size_t)csr[e] * 64 + lane];
  vout[(size_t)wid * 64 + lane] = acc;
}

// thread-per-node GEMM: z[n] = act(vin[n]) @ W + bias, act = BN+ReLU if dobn.
// vin/zout may alias (in-place safe: each block reads only its own 256 rows,
// all staging reads complete before the post-loop stores).
__global__ __launch_bounds__(256) void k_gemm(
    const float* vin, float* zout, const float* __restrict__ W,
    const float* __restrict__ bias, const float* __restrict__ AB, int dobn, int N) {
  __shared__ float vs[256 * 17];
  int tid = threadIdx.x;
  int n0 = blockIdx.x * 256;
  int n = n0 + tid;
  float acc[64];
#pragma unroll
  for (int d = 0; d < 64; d++) acc[d] = 0.f;
#pragma unroll 1
  for (int fb = 0; fb < 64; fb += 16) {
    __syncthreads();
#pragma unroll
    for (int g = 0; g < 4; g++) {  // stage 256 rows x 16 cols, coalesced
      int r = g * 64 + (tid >> 2);
      int q = tid & 3;
      int rn = n0 + r;
      float4 t = (rn < N) ? *(const float4*)(vin + (size_t)rn * 64 + fb + 4 * q)
                          : make_float4(0.f, 0.f, 0.f, 0.f);
      int base = r * 17 + 4 * q;
      vs[base] = t.x;
      vs[base + 1] = t.y;
      vs[base + 2] = t.z;
      vs[base + 3] = t.w;
    }
    __syncthreads();
    for (int fc = 0; fc < 16; fc++) {
      int f = fb + fc;
      float vf = vs[tid * 17 + fc];
      if (dobn) vf = fmaxf(vf * AB[f] + AB[64 + f], 0.f);
      const float* wr = W + f * 64;  // wave-uniform -> s_loads
#pragma unroll
      for (int d = 0; d < 64; d++) acc[d] += vf * wr[d];
    }
  }
  if (n < N) {
    float* zr = zout + (size_t)n * 64;
#pragma unroll
    for (int d = 0; d < 64; d += 4)
      *(float4*)(zr + d) = make_float4(acc[d] + bias[d], acc[d + 1] + bias[d + 1],
                                       acc[d + 2] + bias[d + 2], acc[d + 3] + bias[d + 3]);
  }
}

// column sums/sumsq: grid-stride with stride % 64 == 0 so lane <-> column.
__global__ void k_colstats(const float* __restrict__ z, float* __restrict__ partials,
                           int N) {
  __shared__ float ls[4 * 64], ls2[4 * 64];
  int lane = threadIdx.x & 63;
  int w = threadIdx.x >> 6;
  float s = 0.f, s2 = 0.f;
  size_t total = (size_t)N * 64;
  size_t stride = (size_t)gridDim.x * blockDim.x;
  for (size_t i = (size_t)blockIdx.x * blockDim.x + threadIdx.x; i < total; i += stride) {
    float x = z[i];
    s += x;
    s2 += x * x;
  }
  ls[w * 64 + lane] = s;
  ls2[w * 64 + lane] = s2;
  __syncthreads();
  if (threadIdx.x < 64) {
    float a = 0.f, b = 0.f;
#pragma unroll
    for (int ww = 0; ww < 4; ww++) {
      a += ls[ww * 64 + threadIdx.x];
      b += ls2[ww * 64 + threadIdx.x];
    }
    partials[blockIdx.x * 128 + threadIdx.x] = a;
    partials[blockIdx.x * 128 + 64 + threadIdx.x] = b;
  }
}

__global__ void k_bnfin(const float* __restrict__ partials, int nparts,
                        const float* __restrict__ g, const float* __restrict__ be,
                        float* __restrict__ AB, int N) {
  int f = threadIdx.x;
  if (f < 64) {
    float s = 0.f, s2 = 0.f;
    for (int p = 0; p < nparts; p++) {
      s += partials[p * 128 + f];
      s2 += partials[p * 128 + 64 + f];
    }
    float inv_n = 1.f / (float)N;
    float mu = s * inv_n;
    float var = s2 * inv_n - mu * mu;
    float is = rsqrtf(var + BN_EPS);
    float A = is * g[f];
    AB[f] = A;
    AB[64 + f] = be[f] - mu * A;
  }
}

// logits[n] = x[n] @ fcW0 + sum_l fcb[l]
__global__ __launch_bounds__(256) void k_head_init(
    const float* __restrict__ x, const float* __restrict__ fcW0,
    const float* __restrict__ fcb, float* __restrict__ logits, int N) {
  __shared__ float vs[256 * 17];
  int tid = threadIdx.x;
  int n0 = blockIdx.x * 256;
  int n = n0 + tid;
  float acc[10];
#pragma unroll
  for (int c = 0; c < 10; c++) acc[c] = 0.f;
#pragma unroll 1
  for (int fb = 0; fb < 64; fb += 16) {
    __syncthreads();
#pragma unroll
    for (int g = 0; g < 4; g++) {
      int r = g * 64 + (tid >> 2);
      int q = tid & 3;
      int rn = n0 + r;
      float4 t = (rn < N) ? *(const float4*)(x + (size_t)rn * 64 + fb + 4 * q)
                          : make_float4(0.f, 0.f, 0.f, 0.f);
      int base = r * 17 + 4 * q;
      vs[base] = t.x;
      vs[base + 1] = t.y;
      vs[base + 2] = t.z;
      vs[base + 3] = t.w;
    }
    __syncthreads();
    for (int fc = 0; fc < 16; fc++) {
      int f = fb + fc;
      float vf = vs[tid * 17 + fc];
      const float* wr = fcW0 + f * 10;
#pragma unroll
      for (int c = 0; c < 10; c++) acc[c] += vf * wr[c];
    }
  }
  if (n < N) {
    float* lr = logits + (size_t)n * 10;
#pragma unroll
    for (int c = 0; c < 10; c++)
      lr[c] = acc[c] + (fcb[c] + fcb[10 + c] + fcb[20 + c] + fcb[30 + c]);
  }
}

// h = relu(z*A+B); store h; logits += h @ fcWl
__global__ __launch_bounds__(256) void k_bn_head(
    const float* __restrict__ z, const float* __restrict__ AB,
    float* __restrict__ hout, const float* __restrict__ fcWl,
    float* __restrict__ logits, int N) {
  __shared__ float vs[256 * 17];
  int tid = threadIdx.x;
  int n0 = blockIdx.x * 256;
  int n = n0 + tid;
  float acc[10];
#pragma unroll
  for (int c = 0; c < 10; c++) acc[c] = 0.f;
#pragma unroll 1
  for (int fb = 0; fb < 64; fb += 16) {
    __syncthreads();
#pragma unroll
    for (int g = 0; g < 4; g++) {
      int r = g * 64 + (tid >> 2);
      int q = tid & 3;
      int rn = n0 + r;
      float4 t = (rn < N) ? *(const float4*)(z + (size_t)rn * 64 + fb + 4 * q)
                          : make_float4(0.f, 0.f, 0.f, 0.f);
      int base = r * 17 + 4 * q;
      vs[base] = t.x;
      vs[base + 1] = t.y;
      vs[base + 2] = t.z;
      vs[base + 3] = t.w;
    }
    __syncthreads();
    float tl[16];
#pragma unroll
    for (int fc = 0; fc < 16; fc++) {
      int f = fb + fc;
      float val = vs[tid * 17 + fc] * AB[f] + AB[64 + f];
      tl[fc] = fmaxf(val, 0.f);
      const float* wr = fcWl + f * 10;
#pragma unroll
      for (int c = 0; c < 10; c++) acc[c] += tl[fc] * wr[c];
    }
    __syncthreads();
#pragma unroll
    for (int fc = 0; fc < 16; fc++) vs[tid * 17 + fc] = tl[fc];
    __syncthreads();
#pragma unroll
    for (int g = 0; g < 4; g++) {  // coalesced h store via LDS bounce
      int r = g * 64 + (tid >> 2);
      int q = tid & 3;
      int rn = n0 + r;
      if (rn < N) {
        int base = r * 17 + 4 * q;
        *(float4*)(hout + (size_t)rn * 64 + fb + 4 * q) =
            make_float4(vs[base], vs[base + 1], vs[base + 2], vs[base + 3]);
      }
    }
  }
  if (n < N) {
    float* lr = logits + (size_t)n * 10;
#pragma unroll
    for (int c = 0; c < 10; c++) lr[c] += acc[c];
  }
}

__global__ void k_logsoftmax(const float* __restrict__ logits, float* __restrict__ out,
                             int N) {
  int n = blockIdx.x * blockDim.x + threadIdx.x;
  if (n >= N) return;
  const float* lr = logits + (size_t)n * 10;
  float v[10];
  float m = -INFINITY;
#pragma unroll
  for (int c = 0; c < 10; c++) {
    v[c] = lr[c];
    m = fmaxf(m, v[c]);
  }
  float s = 0.f;
#pragma unroll
  for (int c = 0; c < 10; c++) s += expf(v[c] - m);
  float l = logf(s) + m;
  float* orow = out + (size_t)n * 10;
#pragma unroll
  for (int c = 0; c < 10; c++) orow[c] = v[c] - l;
}

extern "C" void kernel_launch(void* const* d_in, const int* in_sizes, int n_in,
                              void* d_out, int out_size, void* d_ws, size_t ws_size,
                              hipStream_t stream) {
  const float* x = (const float*)d_in[0];
  const int* ei = (const int*)d_in[1];
  const float* W1 = (const float*)d_in[2];
  const float* b1 = (const float*)d_in[3];
  const float* g1 = (const float*)d_in[4];
  const float* be1 = (const float*)d_in[5];
  const float* W2 = (const float*)d_in[6];
  const float* b2 = (const float*)d_in[7];
  const float* gbn = (const float*)d_in[8];
  const float* bbn = (const float*)d_in[9];
  const float* fcW = (const float*)d_in[10];
  const float* fcb = (const float*)d_in[11];
  float* out = (float*)d_out;

  const int N = in_sizes[0] / 64;
  const int E = in_sizes[1] / 2;
  const int* src = ei;
  const int* dst = ei + E;

  char* ws = (char*)d_ws;
  size_t off = 0;
  auto alloc = [&](size_t bytes) -> void* {
    void* p = ws + off;
    off = (off + bytes + 255) & ~(size_t)255;
    return p;
  };
  int* counts = (int*)alloc((size_t)N * 4);
  int* offs = (int*)alloc((size_t)(N + 1) * 4);
  int* cursor = (int*)alloc((size_t)N * 4);
  int* csr = (int*)alloc((size_t)E * 4);
  float* hbuf = (float*)alloc((size_t)N * 64 * 4);
  float* zbuf = (float*)alloc((size_t)N * 64 * 4);
  float* vbuf = (float*)alloc((size_t)N * 64 * 4);
  float* logits = (float*)alloc((size_t)N * 10 * 4);
  float* partials = (float*)alloc(256 * 128 * 4);
  float* AB = (float*)alloc(128 * 4);
  int* blocksums = (int*)alloc(256 * 4);
  int* blockoffs = (int*)alloc(256 * 4);
  (void)ws_size;
  (void)n_in;
  (void)out_size;

  hipMemsetAsync(counts, 0, (size_t)N * 4, stream);
  int eb = (E + 255) / 256;
  int nb = (N + 255) / 256;
  int nscan = (N + SCAN_CHUNK - 1) / SCAN_CHUNK;  // <=256 by construction
  k_hist<<<eb, 256, 0, stream>>>(dst, counts, E);
  k_blocksum<<<nscan, 256, 0, stream>>>(counts, blocksums, N);
  k_scanblock<<<1, 256, 0, stream>>>(blocksums, blockoffs, nscan);
  k_scanfinal<<<nscan, 256, 0, stream>>>(counts, blockoffs, offs, cursor, N);
  k_scatter<<<eb, 256, 0, stream>>>(src, dst, cursor, csr, E);
  k_head_init<<<nb, 256, 0, stream>>>(x, fcW, fcb, logits, N);

  const float* hin = x;
  for (int l = 0; l < 3; l++) {
    k_agg<<<(N * 64 + 255) / 256, 256, 0, stream>>>(hin, offs, csr, vbuf, N);
    k_gemm<<<nb, 256, 0, stream>>>(vbuf, zbuf, W1 + l * 4096, b1 + l * 64, AB, 0, N);
    k_colstats<<<256, 256, 0, stream>>>(zbuf, partials, N);
    k_bnfin<<<1, 64, 0, stream>>>(partials, 256, g1 + l * 64, be1 + l * 64, AB, N);
    k_gemm<<<nb, 256, 0, stream>>>(zbuf, zbuf, W2 + l * 4096, b2 + l * 64, AB, 1, N);
    k_colstats<<<256, 256, 0, stream>>>(zbuf, partials, N);
    k_bnfin<<<1, 64, 0, stream>>>(partials, 256, gbn + l * 64, bbn + l * 64, AB, N);
    k_bn_head<<<nb, 256, 0, stream>>>(zbuf, AB, hbuf, fcW + (l + 1) * 640, logits, N);
    hin = hbuf;
  }
  k_logsoftmax<<<nb, 256, 0, stream>>>(logits, out, N);
}

// Round 3
// 1243.790 us; speedup vs baseline: 1.5059x; 1.3198x over previous
//
#include <hip/hip_runtime.h>
#include <math.h>

// GIN: N=100000 nodes, E=1600000 edges, F=D=64, L=3 layers, C=10 classes.
// R3 changes:
//   - CSR build via two-phase bucket partition (bucket = dst>>9): kills the
//     105MB write-amplification of the random 4B scatter (was 131 us).
//   - BN column stats fused into k_gemm epilogue (xor-fold shuffle reduction,
//     lane l ends owning column l): removes 6 k_colstats full passes.

#define BN_EPS 1e-5f
#define SCAN_CHUNK 512  // elements per block in node-level scan (N<=131072)
#define NBKT 256        // dst buckets (dst>>9 -> <=196 used)
#define PCHUNK 8192     // edges per partition block

// ---------- CSR build ----------

// bucket histogram (grid-stride, LDS-combined)
__global__ __launch_bounds__(256) void k_buckethist(const int* __restrict__ dst,
                                                    int* __restrict__ bcnt, int E) {
  __shared__ int lh[NBKT];
  lh[threadIdx.x] = 0;
  __syncthreads();
  for (int e = blockIdx.x * 256 + threadIdx.x; e < E; e += gridDim.x * 256)
    atomicAdd(&lh[dst[e] >> 9], 1);
  __syncthreads();
  int c = lh[threadIdx.x];
  if (c) atomicAdd(&bcnt[threadIdx.x], c);
}

// single-block exclusive scan of <=256 values
__global__ __launch_bounds__(256) void k_scanblock(const int* __restrict__ sums,
                                                   int* __restrict__ excl, int nblk) {
  __shared__ int ts[256];
  int t = threadIdx.x;
  int v = (t < nblk) ? sums[t] : 0;
  ts[t] = v;
  __syncthreads();
  for (int o = 1; o < 256; o <<= 1) {
    int add = (t >= o) ? ts[t - o] : 0;
    __syncthreads();
    ts[t] += add;
    __syncthreads();
  }
  excl[t] = ts[t] - v;
}

// partition edges into dst-buckets; per-block contiguous runs per bucket
__global__ __launch_bounds__(256) void k_partition(const int* __restrict__ src,
                                                   const int* __restrict__ dst,
                                                   int* __restrict__ bcur,
                                                   int2* __restrict__ ep, int E) {
  __shared__ int lh[NBKT];
  __shared__ int lbase[NBKT];
  __shared__ int lcur[NBKT];
  int base = blockIdx.x * PCHUNK;
  int end = min(base + PCHUNK, E);
  lh[threadIdx.x] = 0;
  lcur[threadIdx.x] = 0;
  __syncthreads();
  for (int e = base + threadIdx.x; e < end; e += 256) atomicAdd(&lh[dst[e] >> 9], 1);
  __syncthreads();
  int c = lh[threadIdx.x];
  lbase[threadIdx.x] = c ? atomicAdd(&bcur[threadIdx.x], c) : 0;
  __syncthreads();
  for (int e = base + threadIdx.x; e < end; e += 256) {
    int d = dst[e];
    int b = d >> 9;
    int r = atomicAdd(&lcur[b], 1);
    ep[lbase[b] + r] = make_int2(src[e], d);
  }
}

// exact per-node hist from bucketed edges (atomics hit a 2KB window per block)
__global__ void k_hist2(const int2* __restrict__ ep, int* __restrict__ counts, int E) {
  int e = blockIdx.x * blockDim.x + threadIdx.x;
  if (e < E) atomicAdd(&counts[ep[e].y], 1);
}

// node-level scan pass 1: per-block sums of 512-element chunks
__global__ __launch_bounds__(256) void k_blocksum(const int* __restrict__ counts,
                                                  int* __restrict__ blocksums, int N) {
  __shared__ int ls[256];
  int t = threadIdx.x;
  int base = blockIdx.x * SCAN_CHUNK;
  int i0 = base + 2 * t, i1 = i0 + 1;
  int c0 = (i0 < N) ? counts[i0] : 0;
  int c1 = (i1 < N) ? counts[i1] : 0;
  ls[t] = c0 + c1;
  __syncthreads();
  for (int o = 128; o > 0; o >>= 1) {
    if (t < o) ls[t] += ls[t + o];
    __syncthreads();
  }
  if (t == 0) blocksums[blockIdx.x] = ls[0];
}

// node-level scan pass 3
__global__ __launch_bounds__(256) void k_scanfinal(
    const int* __restrict__ counts, const int* __restrict__ blockoffs,
    int* __restrict__ offs, int* __restrict__ cursor, int N) {
  __shared__ int ts[256];
  int t = threadIdx.x;
  int base = blockIdx.x * SCAN_CHUNK;
  int i0 = base + 2 * t, i1 = i0 + 1;
  int c0 = (i0 < N) ? counts[i0] : 0;
  int c1 = (i1 < N) ? counts[i1] : 0;
  int s = c0 + c1;
  ts[t] = s;
  __syncthreads();
  for (int o = 1; o < 256; o <<= 1) {
    int add = (t >= o) ? ts[t - o] : 0;
    __syncthreads();
    ts[t] += add;
    __syncthreads();
  }
  int excl = ts[t] - s + blockoffs[blockIdx.x];
  if (i0 < N) {
    offs[i0] = excl;
    cursor[i0] = excl;
  }
  if (i1 < N) {
    offs[i1] = excl + c0;
    cursor[i1] = excl + c0;
  }
  if (i0 == N - 1) offs[N] = excl + c0;
  else if (i1 == N - 1) offs[N] = excl + c0 + c1;
}

// final scatter from bucketed edges: cursor + csr writes stay in an L2-hot window
__global__ void k_scatter2(const int2* __restrict__ ep, int* __restrict__ cursor,
                           int* __restrict__ csr, int E) {
  int e = blockIdx.x * blockDim.x + threadIdx.x;
  if (e < E) {
    int2 p = ep[e];
    int pos = atomicAdd(&cursor[p.y], 1);
    csr[pos] = p.x;
  }
}

// ---------- compute ----------

// wave-per-node aggregation: v[n] = h[n] + sum_{e in CSR[n]} h[src_e]
__global__ __launch_bounds__(256) void k_agg(
    const float* __restrict__ h, const int* __restrict__ offs,
    const int* __restrict__ csr, float* __restrict__ vout, int N) {
  int gid = blockIdx.x * blockDim.x + threadIdx.x;
  int wid = __builtin_amdgcn_readfirstlane(gid >> 6);  // node id, wave-uniform
  int lane = threadIdx.x & 63;
  if (wid >= N) return;
  int e0 = offs[wid];
  int e1 = offs[wid + 1];
  float acc = h[(size_t)wid * 64 + lane];
  int e = e0;
  for (; e + 4 <= e1; e += 4) {  // 4 gathers in flight
    int s0 = csr[e], s1 = csr[e + 1], s2 = csr[e + 2], s3 = csr[e + 3];
    float a0 = h[(size_t)s0 * 64 + lane];
    float a1 = h[(size_t)s1 * 64 + lane];
    float a2 = h[(size_t)s2 * 64 + lane];
    float a3 = h[(size_t)s3 * 64 + lane];
    acc += a0 + a1 + a2 + a3;
  }
  for (; e < e1; e++) acc += h[(size_t)csr[e] * 64 + lane];
  vout[(size_t)wid * 64 + lane] = acc;
}

// thread-per-node GEMM: z[n] = act(vin[n]) @ W + bias, act = BN+ReLU if dobn.
// Epilogue: column sums/sumsq of z via xor-fold shuffle reduction (lane l ends
// holding column l's wave-sum), LDS combine, atomicAdd into stats[128].
__global__ __launch_bounds__(256) void k_gemm(
    const float* vin, float* zout, const float* __restrict__ W,
    const float* __restrict__ bias, const float* __restrict__ AB, int dobn,
    float* __restrict__ stats, int N) {
  __shared__ float vs[256 * 17];
  int tid = threadIdx.x;
  int n0 = blockIdx.x * 256;
  int n = n0 + tid;
  float acc[64];
#pragma unroll
  for (int d = 0; d < 64; d++) acc[d] = 0.f;
#pragma unroll 1
  for (int fb = 0; fb < 64; fb += 16) {
    __syncthreads();
#pragma unroll
    for (int g = 0; g < 4; g++) {  // stage 256 rows x 16 cols, coalesced
      int r = g * 64 + (tid >> 2);
      int q = tid & 3;
      int rn = n0 + r;
      float4 t = (rn < N) ? *(const float4*)(vin + (size_t)rn * 64 + fb + 4 * q)
                          : make_float4(0.f, 0.f, 0.f, 0.f);
      int base = r * 17 + 4 * q;
      vs[base] = t.x;
      vs[base + 1] = t.y;
      vs[base + 2] = t.z;
      vs[base + 3] = t.w;
    }
    __syncthreads();
    for (int fc = 0; fc < 16; fc++) {
      int f = fb + fc;
      float vf = vs[tid * 17 + fc];
      if (dobn) vf = fmaxf(vf * AB[f] + AB[64 + f], 0.f);
      const float* wr = W + f * 64;  // wave-uniform -> s_loads
#pragma unroll
      for (int d = 0; d < 64; d++) acc[d] += vf * wr[d];
    }
  }
#pragma unroll
  for (int d = 0; d < 64; d++) acc[d] += bias[d];
  if (n < N) {
    float* zr = zout + (size_t)n * 64;
#pragma unroll
    for (int d = 0; d < 64; d += 4)
      *(float4*)(zr + d) = make_float4(acc[d], acc[d + 1], acc[d + 2], acc[d + 3]);
  } else {
#pragma unroll
    for (int d = 0; d < 64; d++) acc[d] = 0.f;  // no stats contribution
  }
  // xor-fold: lane l ends holding sum/sumsq for column l across its wave
  int lane = tid & 63;
  int w = tid >> 6;
  float s[32], q[32];
  {
    bool hb = (lane & 32) != 0;
#pragma unroll
    for (int r = 0; r < 32; r++) {
      float lo = acc[r], hi = acc[r + 32];
      float ks = hb ? hi : lo, ss = hb ? lo : hi;
      s[r] = ks + __shfl_xor(ss, 32);
      float kq = ks * ks, sq = ss * ss;
      q[r] = kq + __shfl_xor(sq, 32);
    }
  }
#pragma unroll
  for (int m = 16; m >= 1; m >>= 1) {
    bool hb = (lane & m) != 0;
#pragma unroll
    for (int r = 0; r < m; r++) {
      float ks = hb ? s[r + m] : s[r], ss = hb ? s[r] : s[r + m];
      s[r] = ks + __shfl_xor(ss, m);
      float kq = hb ? q[r + m] : q[r], sq = hb ? q[r] : q[r + m];
      q[r] = kq + __shfl_xor(sq, m);
    }
  }
  __syncthreads();  // vs free for reuse
  vs[w * 64 + lane] = s[0];
  vs[256 + w * 64 + lane] = q[0];
  __syncthreads();
  if (tid < 64) {
    float a = vs[tid] + vs[64 + tid] + vs[128 + tid] + vs[192 + tid];
    float b = vs[256 + tid] + vs[320 + tid] + vs[384 + tid] + vs[448 + tid];
    atomicAdd(&stats[tid], a);
    atomicAdd(&stats[64 + tid], b);
  }
}

__global__ void k_bnfin(const float* __restrict__ stats, const float* __restrict__ g,
                        const float* __restrict__ be, float* __restrict__ AB, int N) {
  int f = threadIdx.x;
  if (f < 64) {
    float inv_n = 1.f / (float)N;
    float mu = stats[f] * inv_n;
    float var = stats[64 + f] * inv_n - mu * mu;
    float is = rsqrtf(var + BN_EPS);
    float A = is * g[f];
    AB[f] = A;
    AB[64 + f] = be[f] - mu * A;
  }
}

// logits[n] = x[n] @ fcW0 + sum_l fcb[l]
__global__ __launch_bounds__(256) void k_head_init(
    const float* __restrict__ x, const float* __restrict__ fcW0,
    const float* __restrict__ fcb, float* __restrict__ logits, int N) {
  __shared__ float vs[256 * 17];
  int tid = threadIdx.x;
  int n0 = blockIdx.x * 256;
  int n = n0 + tid;
  float acc[10];
#pragma unroll
  for (int c = 0; c < 10; c++) acc[c] = 0.f;
#pragma unroll 1
  for (int fb = 0; fb < 64; fb += 16) {
    __syncthreads();
#pragma unroll
    for (int g = 0; g < 4; g++) {
      int r = g * 64 + (tid >> 2);
      int q = tid & 3;
      int rn = n0 + r;
      float4 t = (rn < N) ? *(const float4*)(x + (size_t)rn * 64 + fb + 4 * q)
                          : make_float4(0.f, 0.f, 0.f, 0.f);
      int base = r * 17 + 4 * q;
      vs[base] = t.x;
      vs[base + 1] = t.y;
      vs[base + 2] = t.z;
      vs[base + 3] = t.w;
    }
    __syncthreads();
    for (int fc = 0; fc < 16; fc++) {
      int f = fb + fc;
      float vf = vs[tid * 17 + fc];
      const float* wr = fcW0 + f * 10;
#pragma unroll
      for (int c = 0; c < 10; c++) acc[c] += vf * wr[c];
    }
  }
  if (n < N) {
    float* lr = logits + (size_t)n * 10;
#pragma unroll
    for (int c = 0; c < 10; c++)
      lr[c] = acc[c] + (fcb[c] + fcb[10 + c] + fcb[20 + c] + fcb[30 + c]);
  }
}

// h = relu(z*A+B); store h; logits += h @ fcWl
__global__ __launch_bounds__(256) void k_bn_head(
    const float* __restrict__ z, const float* __restrict__ AB,
    float* __restrict__ hout, const float* __restrict__ fcWl,
    float* __restrict__ logits, int N) {
  __shared__ float vs[256 * 17];
  int tid = threadIdx.x;
  int n0 = blockIdx.x * 256;
  int n = n0 + tid;
  float acc[10];
#pragma unroll
  for (int c = 0; c < 10; c++) acc[c] = 0.f;
#pragma unroll 1
  for (int fb = 0; fb < 64; fb += 16) {
    __syncthreads();
#pragma unroll
    for (int g = 0; g < 4; g++) {
      int r = g * 64 + (tid >> 2);
      int q = tid & 3;
      int rn = n0 + r;
      float4 t = (rn < N) ? *(const float4*)(z + (size_t)rn * 64 + fb + 4 * q)
                          : make_float4(0.f, 0.f, 0.f, 0.f);
      int base = r * 17 + 4 * q;
      vs[base] = t.x;
      vs[base + 1] = t.y;
      vs[base + 2] = t.z;
      vs[base + 3] = t.w;
    }
    __syncthreads();
    float tl[16];
#pragma unroll
    for (int fc = 0; fc < 16; fc++) {
      int f = fb + fc;
      float val = vs[tid * 17 + fc] * AB[f] + AB[64 + f];
      tl[fc] = fmaxf(val, 0.f);
      const float* wr = fcWl + f * 10;
#pragma unroll
      for (int c = 0; c < 10; c++) acc[c] += tl[fc] * wr[c];
    }
    __syncthreads();
#pragma unroll
    for (int fc = 0; fc < 16; fc++) vs[tid * 17 + fc] = tl[fc];
    __syncthreads();
#pragma unroll
    for (int g = 0; g < 4; g++) {  // coalesced h store via LDS bounce
      int r = g * 64 + (tid >> 2);
      int q = tid & 3;
      int rn = n0 + r;
      if (rn < N) {
        int base = r * 17 + 4 * q;
        *(float4*)(hout + (size_t)rn * 64 + fb + 4 * q) =
            make_float4(vs[base], vs[base + 1], vs[base + 2], vs[base + 3]);
      }
    }
  }
  if (n < N) {
    float* lr = logits + (size_t)n * 10;
#pragma unroll
    for (int c = 0; c < 10; c++) lr[c] += acc[c];
  }
}

__global__ void k_logsoftmax(const float* __restrict__ logits, float* __restrict__ out,
                             int N) {
  int n = blockIdx.x * blockDim.x + threadIdx.x;
  if (n >= N) return;
  const float* lr = logits + (size_t)n * 10;
  float v[10];
  float m = -INFINITY;
#pragma unroll
  for (int c = 0; c < 10; c++) {
    v[c] = lr[c];
    m = fmaxf(m, v[c]);
  }
  float s = 0.f;
#pragma unroll
  for (int c = 0; c < 10; c++) s += expf(v[c] - m);
  float l = logf(s) + m;
  float* orow = out + (size_t)n * 10;
#pragma unroll
  for (int c = 0; c < 10; c++) orow[c] = v[c] - l;
}

extern "C" void kernel_launch(void* const* d_in, const int* in_sizes, int n_in,
                              void* d_out, int out_size, void* d_ws, size_t ws_size,
                              hipStream_t stream) {
  const float* x = (const float*)d_in[0];
  const int* ei = (const int*)d_in[1];
  const float* W1 = (const float*)d_in[2];
  const float* b1 = (const float*)d_in[3];
  const float* g1 = (const float*)d_in[4];
  const float* be1 = (const float*)d_in[5];
  const float* W2 = (const float*)d_in[6];
  const float* b2 = (const float*)d_in[7];
  const float* gbn = (const float*)d_in[8];
  const float* bbn = (const float*)d_in[9];
  const float* fcW = (const float*)d_in[10];
  const float* fcb = (const float*)d_in[11];
  float* out = (float*)d_out;

  const int N = in_sizes[0] / 64;
  const int E = in_sizes[1] / 2;
  const int* src = ei;
  const int* dst = ei + E;

  char* ws = (char*)d_ws;
  size_t off = 0;
  auto alloc = [&](size_t bytes) -> void* {
    void* p = ws + off;
    off = (off + bytes + 255) & ~(size_t)255;
    return p;
  };
  // zero-initialized region (single memset): counts + bcnt + stats
  int* counts = (int*)alloc((size_t)N * 4);
  int* bcnt = (int*)alloc(NBKT * 4);
  float* stats = (float*)alloc(6 * 128 * 4);
  size_t zspan = off;  // memset [ws, ws+zspan)
  float* AB = (float*)alloc(128 * 4);
  int* bcur = (int*)alloc(NBKT * 4);
  int* offs = (int*)alloc((size_t)(N + 1) * 4);
  int* cursor = (int*)alloc((size_t)N * 4);
  int* csr = (int*)alloc((size_t)E * 4);
  float* hbuf = (float*)alloc((size_t)N * 64 * 4);
  float* zbuf = (float*)alloc((size_t)N * 64 * 4);
  float* vbuf = (float*)alloc((size_t)N * 64 * 4);
  float* logits = (float*)alloc((size_t)N * 10 * 4);
  int* blocksums = (int*)alloc(256 * 4);
  int* blockoffs = (int*)alloc(256 * 4);
  int2* ep = (int2*)vbuf;  // alias: ep is dead before k_agg writes vbuf
  (void)ws_size;
  (void)n_in;
  (void)out_size;

  hipMemsetAsync(ws, 0, zspan, stream);
  int eb = (E + 255) / 256;
  int nb = (N + 255) / 256;
  int nscan = (N + SCAN_CHUNK - 1) / SCAN_CHUNK;  // <=256
  int nparts = (E + PCHUNK - 1) / PCHUNK;
  k_buckethist<<<512, 256, 0, stream>>>(dst, bcnt, E);
  k_scanblock<<<1, 256, 0, stream>>>(bcnt, bcur, NBKT);
  k_partition<<<nparts, 256, 0, stream>>>(src, dst, bcur, ep, E);
  k_hist2<<<eb, 256, 0, stream>>>(ep, counts, E);
  k_blocksum<<<nscan, 256, 0, stream>>>(counts, blocksums, N);
  k_scanblock<<<1, 256, 0, stream>>>(blocksums, blockoffs, nscan);
  k_scanfinal<<<nscan, 256, 0, stream>>>(counts, blockoffs, offs, cursor, N);
  k_scatter2<<<eb, 256, 0, stream>>>(ep, cursor, csr, E);
  k_head_init<<<nb, 256, 0, stream>>>(x, fcW, fcb, logits, N);

  const float* hin = x;
  for (int l = 0; l < 3; l++) {
    float* st1 = stats + (2 * l) * 128;
    float* st2 = stats + (2 * l + 1) * 128;
    k_agg<<<(N * 64 + 255) / 256, 256, 0, stream>>>(hin, offs, csr, vbuf, N);
    k_gemm<<<nb, 256, 0, stream>>>(vbuf, zbuf, W1 + l * 4096, b1 + l * 64, AB, 0, st1, N);
    k_bnfin<<<1, 64, 0, stream>>>(st1, g1 + l * 64, be1 + l * 64, AB, N);
    k_gemm<<<nb, 256, 0, stream>>>(zbuf, zbuf, W2 + l * 4096, b2 + l * 64, AB, 1, st2, N);
    k_bnfin<<<1, 64, 0, stream>>>(st2, gbn + l * 64, bbn + l * 64, AB, N);
    k_bn_head<<<nb, 256, 0, stream>>>(zbuf, AB, hbuf, fcW + (l + 1) * 640, logits, N);
    hin = hbuf;
  }
  k_logsoftmax<<<nb, 256, 0, stream>>>(logits, out, N);
}

// Round 4
// 705.400 us; speedup vs baseline: 2.6553x; 1.7632x over previous
//
#include <hip/hip_runtime.h>
#include <math.h>

// GIN: N=100000 nodes, E=1600000 edges, F=D=64, L=3 layers, C=10 classes.
// R4: k_gemm rewritten (was 6x141us, SMEM-stall serialized W reads in the
// inner loop). New k_gemm2: 128 rows/block (782 blocks), A+W staged in LDS,
// 4x8 register tile per thread, pure ds_read+FMA inner loop. BN+ReLU fused
// into A staging (dobn). b1/b2 dropped: column-constant bias cancels in BN.

#define BN_EPS 1e-5f
#define SCAN_CHUNK 512  // elements per block in node-level scan (N<=131072)
#define NBKT 256        // dst buckets (dst>>9 -> <=196 used)
#define PCHUNK 8192     // edges per partition block

// ---------- CSR build ----------

__global__ __launch_bounds__(256) void k_buckethist(const int* __restrict__ dst,
                                                    int* __restrict__ bcnt, int E) {
  __shared__ int lh[NBKT];
  lh[threadIdx.x] = 0;
  __syncthreads();
  for (int e = blockIdx.x * 256 + threadIdx.x; e < E; e += gridDim.x * 256)
    atomicAdd(&lh[dst[e] >> 9], 1);
  __syncthreads();
  int c = lh[threadIdx.x];
  if (c) atomicAdd(&bcnt[threadIdx.x], c);
}

__global__ __launch_bounds__(256) void k_scanblock(const int* __restrict__ sums,
                                                   int* __restrict__ excl, int nblk) {
  __shared__ int ts[256];
  int t = threadIdx.x;
  int v = (t < nblk) ? sums[t] : 0;
  ts[t] = v;
  __syncthreads();
  for (int o = 1; o < 256; o <<= 1) {
    int add = (t >= o) ? ts[t - o] : 0;
    __syncthreads();
    ts[t] += add;
    __syncthreads();
  }
  excl[t] = ts[t] - v;
}

__global__ __launch_bounds__(256) void k_partition(const int* __restrict__ src,
                                                   const int* __restrict__ dst,
                                                   int* __restrict__ bcur,
                                                   int2* __restrict__ ep, int E) {
  __shared__ int lh[NBKT];
  __shared__ int lbase[NBKT];
  __shared__ int lcur[NBKT];
  int base = blockIdx.x * PCHUNK;
  int end = min(base + PCHUNK, E);
  lh[threadIdx.x] = 0;
  lcur[threadIdx.x] = 0;
  __syncthreads();
  for (int e = base + threadIdx.x; e < end; e += 256) atomicAdd(&lh[dst[e] >> 9], 1);
  __syncthreads();
  int c = lh[threadIdx.x];
  lbase[threadIdx.x] = c ? atomicAdd(&bcur[threadIdx.x], c) : 0;
  __syncthreads();
  for (int e = base + threadIdx.x; e < end; e += 256) {
    int d = dst[e];
    int b = d >> 9;
    int r = atomicAdd(&lcur[b], 1);
    ep[lbase[b] + r] = make_int2(src[e], d);
  }
}

__global__ void k_hist2(const int2* __restrict__ ep, int* __restrict__ counts, int E) {
  int e = blockIdx.x * blockDim.x + threadIdx.x;
  if (e < E) atomicAdd(&counts[ep[e].y], 1);
}

__global__ __launch_bounds__(256) void k_blocksum(const int* __restrict__ counts,
                                                  int* __restrict__ blocksums, int N) {
  __shared__ int ls[256];
  int t = threadIdx.x;
  int base = blockIdx.x * SCAN_CHUNK;
  int i0 = base + 2 * t, i1 = i0 + 1;
  int c0 = (i0 < N) ? counts[i0] : 0;
  int c1 = (i1 < N) ? counts[i1] : 0;
  ls[t] = c0 + c1;
  __syncthreads();
  for (int o = 128; o > 0; o >>= 1) {
    if (t < o) ls[t] += ls[t + o];
    __syncthreads();
  }
  if (t == 0) blocksums[blockIdx.x] = ls[0];
}

__global__ __launch_bounds__(256) void k_scanfinal(
    const int* __restrict__ counts, const int* __restrict__ blockoffs,
    int* __restrict__ offs, int* __restrict__ cursor, int N) {
  __shared__ int ts[256];
  int t = threadIdx.x;
  int base = blockIdx.x * SCAN_CHUNK;
  int i0 = base + 2 * t, i1 = i0 + 1;
  int c0 = (i0 < N) ? counts[i0] : 0;
  int c1 = (i1 < N) ? counts[i1] : 0;
  int s = c0 + c1;
  ts[t] = s;
  __syncthreads();
  for (int o = 1; o < 256; o <<= 1) {
    int add = (t >= o) ? ts[t - o] : 0;
    __syncthreads();
    ts[t] += add;
    __syncthreads();
  }
  int excl = ts[t] - s + blockoffs[blockIdx.x];
  if (i0 < N) {
    offs[i0] = excl;
    cursor[i0] = excl;
  }
  if (i1 < N) {
    offs[i1] = excl + c0;
    cursor[i1] = excl + c0;
  }
  if (i0 == N - 1) offs[N] = excl + c0;
  else if (i1 == N - 1) offs[N] = excl + c0 + c1;
}

__global__ void k_scatter2(const int2* __restrict__ ep, int* __restrict__ cursor,
                           int* __restrict__ csr, int E) {
  int e = blockIdx.x * blockDim.x + threadIdx.x;
  if (e < E) {
    int2 p = ep[e];
    int pos = atomicAdd(&cursor[p.y], 1);
    csr[pos] = p.x;
  }
}

// ---------- compute ----------

// wave-per-node aggregation: v[n] = h[n] + sum_{e in CSR[n]} h[src_e]
__global__ __launch_bounds__(256) void k_agg(
    const float* __restrict__ h, const int* __restrict__ offs,
    const int* __restrict__ csr, float* __restrict__ vout, int N) {
  int gid = blockIdx.x * blockDim.x + threadIdx.x;
  int wid = __builtin_amdgcn_readfirstlane(gid >> 6);  // node id, wave-uniform
  int lane = threadIdx.x & 63;
  if (wid >= N) return;
  int e0 = offs[wid];
  int e1 = offs[wid + 1];
  float acc = h[(size_t)wid * 64 + lane];
  int e = e0;
  for (; e + 4 <= e1; e += 4) {  // 4 gathers in flight
    int s0 = csr[e], s1 = csr[e + 1], s2 = csr[e + 2], s3 = csr[e + 3];
    float a0 = h[(size_t)s0 * 64 + lane];
    float a1 = h[(size_t)s1 * 64 + lane];
    float a2 = h[(size_t)s2 * 64 + lane];
    float a3 = h[(size_t)s3 * 64 + lane];
    acc += a0 + a1 + a2 + a3;
  }
  for (; e < e1; e++) acc += h[(size_t)csr[e] * 64 + lane];
  vout[(size_t)wid * 64 + lane] = acc;
}

// LDS-tiled GEMM: z[n0..n0+128) = act(vin) @ W, act = BN+ReLU if dobn.
// 256 threads: tr=tid>>3 (0..31) owns 4 rows, tc=tid&7 owns 8 cols.
// Epilogue: column sum/sumsq via xor-fold over tr lane bits -> stats[128].
// In-place safe (block stages its own 128 rows before writing them).
__global__ __launch_bounds__(256) void k_gemm2(
    const float* __restrict__ vin, float* __restrict__ zout,
    const float* __restrict__ W, const float* __restrict__ AB, int dobn,
    float* __restrict__ stats, int N) {
  __shared__ float As[128 * 68];
  __shared__ float Ws[64 * 68];
  int tid = threadIdx.x;
  int n0 = blockIdx.x * 128;
#pragma unroll
  for (int i = 0; i < 4; i++) {  // stage W (64x64), coalesced, 2-way max
    int g = tid + i * 256;
    int r = g >> 4, q = g & 15;
    float4 t = *(const float4*)(W + r * 64 + 4 * q);
    int base = r * 68 + 4 * q;
    Ws[base] = t.x; Ws[base + 1] = t.y; Ws[base + 2] = t.z; Ws[base + 3] = t.w;
  }
#pragma unroll
  for (int i = 0; i < 8; i++) {  // stage A (128x64) with optional BN+ReLU
    int g = tid + i * 256;
    int r = g >> 4, q = g & 15;
    int rn = n0 + r;
    float4 t = make_float4(0.f, 0.f, 0.f, 0.f);
    if (rn < N) t = *(const float4*)(vin + (size_t)rn * 64 + 4 * q);
    if (dobn) {
      float4 a = *(const float4*)(AB + 4 * q);
      float4 b = *(const float4*)(AB + 64 + 4 * q);
      t.x = fmaxf(t.x * a.x + b.x, 0.f);
      t.y = fmaxf(t.y * a.y + b.y, 0.f);
      t.z = fmaxf(t.z * a.z + b.z, 0.f);
      t.w = fmaxf(t.w * a.w + b.w, 0.f);
    }
    int base = r * 68 + 4 * q;
    As[base] = t.x; As[base + 1] = t.y; As[base + 2] = t.z; As[base + 3] = t.w;
  }
  __syncthreads();
  int tr = tid >> 3, tc = tid & 7;
  int ra = tr * 4;
  float acc[4][8];
#pragma unroll
  for (int i = 0; i < 4; i++)
#pragma unroll
    for (int j = 0; j < 8; j++) acc[i][j] = 0.f;
#pragma unroll 4
  for (int k = 0; k < 64; k++) {
    float av[4];
#pragma unroll
    for (int i = 0; i < 4; i++) av[i] = As[(ra + i) * 68 + k];
    const float* wk = &Ws[k * 68 + tc * 8];
    float4 w0 = *(const float4*)wk;
    float4 w1 = *(const float4*)(wk + 4);
    float wv[8] = {w0.x, w0.y, w0.z, w0.w, w1.x, w1.y, w1.z, w1.w};
#pragma unroll
    for (int i = 0; i < 4; i++)
#pragma unroll
      for (int j = 0; j < 8; j++) acc[i][j] += av[i] * wv[j];
  }
  // write z (tail rows were staged as zeros; skip their stores)
#pragma unroll
  for (int i = 0; i < 4; i++) {
    int rn = n0 + ra + i;
    if (rn < N) {
      float* zr = zout + (size_t)rn * 64 + tc * 8;
      *(float4*)zr = make_float4(acc[i][0], acc[i][1], acc[i][2], acc[i][3]);
      *(float4*)(zr + 4) = make_float4(acc[i][4], acc[i][5], acc[i][6], acc[i][7]);
    }
  }
  // column stats: thread partial over its 4 rows, fold over tr lane bits
  float cs[8], cq[8];
#pragma unroll
  for (int j = 0; j < 8; j++) {
    float s = 0.f, q = 0.f;
#pragma unroll
    for (int i = 0; i < 4; i++) {
      s += acc[i][j];
      q += acc[i][j] * acc[i][j];
    }
    cs[j] = s;
    cq[j] = q;
  }
#pragma unroll
  for (int m = 8; m <= 32; m <<= 1) {
#pragma unroll
    for (int j = 0; j < 8; j++) {
      cs[j] += __shfl_xor(cs[j], m);
      cq[j] += __shfl_xor(cq[j], m);
    }
  }
  __syncthreads();  // Ws reusable as scratch now
  int w = tid >> 6;
  if ((tid & 63) < 8) {  // one lane per (wave, tc)
    int c = tc * 8;
#pragma unroll
    for (int j = 0; j < 8; j++) {
      Ws[w * 128 + c + j] = cs[j];
      Ws[w * 128 + 64 + c + j] = cq[j];
    }
  }
  __syncthreads();
  if (tid < 64) {
    float a = Ws[tid] + Ws[128 + tid] + Ws[256 + tid] + Ws[384 + tid];
    float b = Ws[64 + tid] + Ws[192 + tid] + Ws[320 + tid] + Ws[448 + tid];
    atomicAdd(&stats[tid], a);
    atomicAdd(&stats[64 + tid], b);
  }
}

__global__ void k_bnfin(const float* __restrict__ stats, const float* __restrict__ g,
                        const float* __restrict__ be, float* __restrict__ AB, int N) {
  int f = threadIdx.x;
  if (f < 64) {
    float inv_n = 1.f / (float)N;
    float mu = stats[f] * inv_n;
    float var = stats[64 + f] * inv_n - mu * mu;
    float is = rsqrtf(var + BN_EPS);
    float A = is * g[f];
    AB[f] = A;
    AB[64 + f] = be[f] - mu * A;
  }
}

// logits[n] = x[n] @ fcW0 + sum_l fcb[l]
__global__ __launch_bounds__(256) void k_head_init(
    const float* __restrict__ x, const float* __restrict__ fcW0,
    const float* __restrict__ fcb, float* __restrict__ logits, int N) {
  __shared__ float vs[256 * 17];
  int tid = threadIdx.x;
  int n0 = blockIdx.x * 256;
  int n = n0 + tid;
  float acc[10];
#pragma unroll
  for (int c = 0; c < 10; c++) acc[c] = 0.f;
#pragma unroll 1
  for (int fb = 0; fb < 64; fb += 16) {
    __syncthreads();
#pragma unroll
    for (int g = 0; g < 4; g++) {
      int r = g * 64 + (tid >> 2);
      int q = tid & 3;
      int rn = n0 + r;
      float4 t = (rn < N) ? *(const float4*)(x + (size_t)rn * 64 + fb + 4 * q)
                          : make_float4(0.f, 0.f, 0.f, 0.f);
      int base = r * 17 + 4 * q;
      vs[base] = t.x;
      vs[base + 1] = t.y;
      vs[base + 2] = t.z;
      vs[base + 3] = t.w;
    }
    __syncthreads();
    for (int fc = 0; fc < 16; fc++) {
      int f = fb + fc;
      float vf = vs[tid * 17 + fc];
      const float* wr = fcW0 + f * 10;
#pragma unroll
      for (int c = 0; c < 10; c++) acc[c] += vf * wr[c];
    }
  }
  if (n < N) {
    float* lr = logits + (size_t)n * 10;
#pragma unroll
    for (int c = 0; c < 10; c++)
      lr[c] = acc[c] + (fcb[c] + fcb[10 + c] + fcb[20 + c] + fcb[30 + c]);
  }
}

// h = relu(z*A+B); store h; logits += h @ fcWl
__global__ __launch_bounds__(256) void k_bn_head(
    const float* __restrict__ z, const float* __restrict__ AB,
    float* __restrict__ hout, const float* __restrict__ fcWl,
    float* __restrict__ logits, int N) {
  __shared__ float vs[256 * 17];
  int tid = threadIdx.x;
  int n0 = blockIdx.x * 256;
  int n = n0 + tid;
  float acc[10];
#pragma unroll
  for (int c = 0; c < 10; c++) acc[c] = 0.f;
#pragma unroll 1
  for (int fb = 0; fb < 64; fb += 16) {
    __syncthreads();
#pragma unroll
    for (int g = 0; g < 4; g++) {
      int r = g * 64 + (tid >> 2);
      int q = tid & 3;
      int rn = n0 + r;
      float4 t = (rn < N) ? *(const float4*)(z + (size_t)rn * 64 + fb + 4 * q)
                          : make_float4(0.f, 0.f, 0.f, 0.f);
      int base = r * 17 + 4 * q;
      vs[base] = t.x;
      vs[base + 1] = t.y;
      vs[base + 2] = t.z;
      vs[base + 3] = t.w;
    }
    __syncthreads();
    float tl[16];
#pragma unroll
    for (int fc = 0; fc < 16; fc++) {
      int f = fb + fc;
      float val = vs[tid * 17 + fc] * AB[f] + AB[64 + f];
      tl[fc] = fmaxf(val, 0.f);
      const float* wr = fcWl + f * 10;
#pragma unroll
      for (int c = 0; c < 10; c++) acc[c] += tl[fc] * wr[c];
    }
    __syncthreads();
#pragma unroll
    for (int fc = 0; fc < 16; fc++) vs[tid * 17 + fc] = tl[fc];
    __syncthreads();
#pragma unroll
    for (int g = 0; g < 4; g++) {  // coalesced h store via LDS bounce
      int r = g * 64 + (tid >> 2);
      int q = tid & 3;
      int rn = n0 + r;
      if (rn < N) {
        int base = r * 17 + 4 * q;
        *(float4*)(hout + (size_t)rn * 64 + fb + 4 * q) =
            make_float4(vs[base], vs[base + 1], vs[base + 2], vs[base + 3]);
      }
    }
  }
  if (n < N) {
    float* lr = logits + (size_t)n * 10;
#pragma unroll
    for (int c = 0; c < 10; c++) lr[c] += acc[c];
  }
}

__global__ void k_logsoftmax(const float* __restrict__ logits, float* __restrict__ out,
                             int N) {
  int n = blockIdx.x * blockDim.x + threadIdx.x;
  if (n >= N) return;
  const float* lr = logits + (size_t)n * 10;
  float v[10];
  float m = -INFINITY;
#pragma unroll
  for (int c = 0; c < 10; c++) {
    v[c] = lr[c];
    m = fmaxf(m, v[c]);
  }
  float s = 0.f;
#pragma unroll
  for (int c = 0; c < 10; c++) s += expf(v[c] - m);
  float l = logf(s) + m;
  float* orow = out + (size_t)n * 10;
#pragma unroll
  for (int c = 0; c < 10; c++) orow[c] = v[c] - l;
}

extern "C" void kernel_launch(void* const* d_in, const int* in_sizes, int n_in,
                              void* d_out, int out_size, void* d_ws, size_t ws_size,
                              hipStream_t stream) {
  const float* x = (const float*)d_in[0];
  const int* ei = (const int*)d_in[1];
  const float* W1 = (const float*)d_in[2];
  const float* g1 = (const float*)d_in[4];
  const float* be1 = (const float*)d_in[5];
  const float* W2 = (const float*)d_in[6];
  const float* gbn = (const float*)d_in[8];
  const float* bbn = (const float*)d_in[9];
  const float* fcW = (const float*)d_in[10];
  const float* fcb = (const float*)d_in[11];
  float* out = (float*)d_out;

  const int N = in_sizes[0] / 64;
  const int E = in_sizes[1] / 2;
  const int* src = ei;
  const int* dst = ei + E;

  char* ws = (char*)d_ws;
  size_t off = 0;
  auto alloc = [&](size_t bytes) -> void* {
    void* p = ws + off;
    off = (off + bytes + 255) & ~(size_t)255;
    return p;
  };
  // zero-initialized region (single memset): counts + bcnt + stats
  int* counts = (int*)alloc((size_t)N * 4);
  int* bcnt = (int*)alloc(NBKT * 4);
  float* stats = (float*)alloc(6 * 128 * 4);
  size_t zspan = off;  // memset [ws, ws+zspan)
  float* AB = (float*)alloc(128 * 4);
  int* bcur = (int*)alloc(NBKT * 4);
  int* offs = (int*)alloc((size_t)(N + 1) * 4);
  int* cursor = (int*)alloc((size_t)N * 4);
  int* csr = (int*)alloc((size_t)E * 4);
  float* hbuf = (float*)alloc((size_t)N * 64 * 4);
  float* zbuf = (float*)alloc((size_t)N * 64 * 4);
  float* vbuf = (float*)alloc((size_t)N * 64 * 4);
  float* logits = (float*)alloc((size_t)N * 10 * 4);
  int* blocksums = (int*)alloc(256 * 4);
  int* blockoffs = (int*)alloc(256 * 4);
  int2* ep = (int2*)vbuf;  // alias: ep is dead before k_agg writes vbuf
  (void)ws_size;
  (void)n_in;
  (void)out_size;

  hipMemsetAsync(ws, 0, zspan, stream);
  int eb = (E + 255) / 256;
  int nb = (N + 255) / 256;
  int gb = (N + 127) / 128;
  int nscan = (N + SCAN_CHUNK - 1) / SCAN_CHUNK;  // <=256
  int nparts = (E + PCHUNK - 1) / PCHUNK;
  k_buckethist<<<512, 256, 0, stream>>>(dst, bcnt, E);
  k_scanblock<<<1, 256, 0, stream>>>(bcnt, bcur, NBKT);
  k_partition<<<nparts, 256, 0, stream>>>(src, dst, bcur, ep, E);
  k_hist2<<<eb, 256, 0, stream>>>(ep, counts, E);
  k_blocksum<<<nscan, 256, 0, stream>>>(counts, blocksums, N);
  k_scanblock<<<1, 256, 0, stream>>>(blocksums, blockoffs, nscan);
  k_scanfinal<<<nscan, 256, 0, stream>>>(counts, blockoffs, offs, cursor, N);
  k_scatter2<<<eb, 256, 0, stream>>>(ep, cursor, csr, E);
  k_head_init<<<nb, 256, 0, stream>>>(x, fcW, fcb, logits, N);

  const float* hin = x;
  for (int l = 0; l < 3; l++) {
    float* st1 = stats + (2 * l) * 128;
    float* st2 = stats + (2 * l + 1) * 128;
    k_agg<<<(N * 64 + 255) / 256, 256, 0, stream>>>(hin, offs, csr, vbuf, N);
    k_gemm2<<<gb, 256, 0, stream>>>(vbuf, zbuf, W1 + l * 4096, AB, 0, st1, N);
    k_bnfin<<<1, 64, 0, stream>>>(st1, g1 + l * 64, be1 + l * 64, AB, N);
    k_gemm2<<<gb, 256, 0, stream>>>(zbuf, zbuf, W2 + l * 4096, AB, 1, st2, N);
    k_bnfin<<<1, 64, 0, stream>>>(st2, gbn + l * 64, bbn + l * 64, AB, N);
    k_bn_head<<<nb, 256, 0, stream>>>(zbuf, AB, hbuf, fcW + (l + 1) * 640, logits, N);
    hin = hbuf;
  }
  k_logsoftmax<<<nb, 256, 0, stream>>>(logits, out, N);
}